// Round 5
// baseline (46.750 us; speedup 1.0000x reference)
//
#include <hip/hip_runtime.h>
#include <hip/hip_bf16.h>
#include <math.h>

#define D 256
#define S 4096
#define BATCH 4
#define RPB 16         // rows per block in fused kernel
#define DT_CUT 7.0f

typedef __attribute__((ext_vector_type(8))) short short8;
typedef __attribute__((ext_vector_type(4))) float f32x4;

static __device__ __forceinline__ unsigned short f2bf(float x) {
    union { __hip_bfloat16 b; unsigned short u; } cv;
    cv.b = __float2bfloat16(x);    // HW RNE convert
    return cv.u;
}

// ---------------------------------------------------------------------------
// K1: transposed bf16 embedding embT[b][d][j] (+ W->bf16 in blocks 0..255).
// grid = 512 blocks x 256 thr; thread covers 16 freqs of one j (coalesced).
// ---------------------------------------------------------------------------
__global__ __launch_bounds__(256) void embt_kernel(const float* __restrict__ t,
                                                   const float* __restrict__ W,
                                                   unsigned short* __restrict__ embT,
                                                   unsigned short* __restrict__ Wb) {
    int blk = blockIdx.x;
    int tid = threadIdx.x;
    if (blk < 256) Wb[blk * 256 + tid] = f2bf(W[blk * 256 + tid]);

    int b   = blk >> 7;
    int kg  = (blk >> 4) & 7;
    int jc  = blk & 15;
    int j   = jc * 256 + tid;
    float tv = t[b * S + j];
    const float c2 = -0.1038102552f;           // -2*log2(10000)/256
#pragma unroll
    for (int kk = 0; kk < 16; ++kk) {
        int k = kg * 16 + kk;
        float te = tv * exp2f(c2 * (float)(k + 1));
        float sn, cs;
        __sincosf(te, &sn, &cs);
        embT[((size_t)(b * D + 2 * k)) * S + j]     = f2bf(sn);
        embT[((size_t)(b * D + 2 * k + 1)) * S + j] = f2bf(cs);
    }
}

// ---------------------------------------------------------------------------
// K2: fused band-GEMM (MFMA) + LayerNorm + decoder-GEMM (MFMA) + softplus.
// Block = 16 rows x 256 d/e, 4 waves (wave w = d/e slice of 64).
// Both GEMM loops software-pipelined: B-fragments loaded one step ahead.
// ---------------------------------------------------------------------------
__global__ __launch_bounds__(256) void fused_kernel(
    const float* __restrict__ t, const unsigned short* __restrict__ embT,
    const unsigned short* __restrict__ Wb,
    const float* __restrict__ gamma, const float* __restrict__ beta,
    const float* __restrict__ w_t, const float* __restrict__ b_t,
    float* __restrict__ out) {
    int blk  = blockIdx.x;
    int b    = blk >> 8;                 // 256 blocks per batch
    int i0   = (blk & 255) * RPB;
    int tid  = threadIdx.x;
    int w    = tid >> 6;
    int lane = tid & 63;
    int ln15 = lane & 15;
    int kg   = lane >> 4;
    const float* tb = t + b * S;

    float ti = tb[i0 + ln15];
    int irow = i0 + ln15;

    // ---- 64-ary cooperative lower_bound: first j with t[j] >= t[i0]-DT_CUT
    float tcut = tb[i0] - DT_CUT;
    int lo = 0, hi = i0;                 // invariant: t[hi] >= tcut
    while (hi > lo) {
        int step = ((hi - lo) + 63) >> 6;
        int p = min(lo + lane * step, hi);
        unsigned long long mb = __ballot(tb[p] < tcut);
        int cnt = __popcll(mb);
        int nlo = (cnt == 0) ? lo : (lo + (cnt - 1) * step + 1);
        int nhi = (cnt == 0) ? nlo : min(lo + cnt * step, hi);
        lo = nlo; hi = nhi;
    }
    int jmin = lo & ~31;                 // align chunks; extra j's score ~0
    int jmax = i0 + RPB - 1;

    // ---- band GEMM: C[m, d] += scores[m, k] * embT[d, k], pipelined chunks
    f32x4 acc[4];
#pragma unroll
    for (int nt = 0; nt < 4; ++nt) acc[nt] = (f32x4){0.f, 0.f, 0.f, 0.f};

    const unsigned short* ebase = embT + ((size_t)(b * D) + w * 64 + ln15) * S;
    short8 bc0, bc1, bc2, bc3;
    float4 tja, tjb;
    {
        const unsigned short* p = ebase + jmin + kg * 8;
        bc0 = *(const short8*)(p + (size_t)0 * 16 * S);
        bc1 = *(const short8*)(p + (size_t)1 * 16 * S);
        bc2 = *(const short8*)(p + (size_t)2 * 16 * S);
        bc3 = *(const short8*)(p + (size_t)3 * 16 * S);
        int jb = min(jmin + kg * 8, S - 8);
        tja = *(const float4*)&tb[jb];
        tjb = *(const float4*)&tb[jb + 4];
    }

    for (int j0 = jmin; j0 <= jmax; j0 += 32) {
        int jn = j0 + 32;
        bool more = (jn <= jmax);
        short8 nb0, nb1, nb2, nb3;
        float4 ntja, ntjb;
        if (more) {                       // prefetch next chunk (uniform branch)
            const unsigned short* p = ebase + jn + kg * 8;
            nb0 = *(const short8*)(p + (size_t)0 * 16 * S);
            nb1 = *(const short8*)(p + (size_t)1 * 16 * S);
            nb2 = *(const short8*)(p + (size_t)2 * 16 * S);
            nb3 = *(const short8*)(p + (size_t)3 * 16 * S);
            int jb = min(jn + kg * 8, S - 8);
            ntja = *(const float4*)&tb[jb];
            ntjb = *(const float4*)&tb[jb + 4];
        }
        // scores for current chunk (overlaps prefetch latency)
        float tj[8] = {tja.x, tja.y, tja.z, tja.w, tjb.x, tjb.y, tjb.z, tjb.w};
        union { short8 v; unsigned short u[8]; } a;
        if (j0 + 31 <= i0) {              // fully causal chunk
#pragma unroll
            for (int e = 0; e < 8; ++e) {
                float dt = ti - tj[e];
                a.u[e] = f2bf(__expf(-0.5f * dt * dt));
            }
        } else {                          // diagonal chunk: mask j > i
#pragma unroll
            for (int e = 0; e < 8; ++e) {
                float dt = ti - tj[e];
                float sc = __expf(-0.5f * dt * dt);
                a.u[e] = (j0 + kg * 8 + e <= irow) ? f2bf(sc) : (unsigned short)0;
            }
        }
        acc[0] = __builtin_amdgcn_mfma_f32_16x16x32_bf16(a.v, bc0, acc[0], 0, 0, 0);
        acc[1] = __builtin_amdgcn_mfma_f32_16x16x32_bf16(a.v, bc1, acc[1], 0, 0, 0);
        acc[2] = __builtin_amdgcn_mfma_f32_16x16x32_bf16(a.v, bc2, acc[2], 0, 0, 0);
        acc[3] = __builtin_amdgcn_mfma_f32_16x16x32_bf16(a.v, bc3, acc[3], 0, 0, 0);
        bc0 = nb0; bc1 = nb1; bc2 = nb2; bc3 = nb3;
        tja = ntja; tjb = ntjb;
    }

    // ---- LayerNorm (row r = kg*4 + reg per lane; col = w*64 + nt*16 + ln15)
    __shared__ float2 s_ln[4][RPB];
    __shared__ unsigned short H[RPB][264];       // +8 pad: conflict-free b128
    __shared__ float s_dec[4][RPB];

#pragma unroll
    for (int reg = 0; reg < 4; ++reg) {
        float s = acc[0][reg] + acc[1][reg] + acc[2][reg] + acc[3][reg];
        float q = acc[0][reg] * acc[0][reg] + acc[1][reg] * acc[1][reg]
                + acc[2][reg] * acc[2][reg] + acc[3][reg] * acc[3][reg];
#pragma unroll
        for (int m = 1; m < 16; m <<= 1) {
            s += __shfl_xor(s, m);
            q += __shfl_xor(q, m);
        }
        if (ln15 == 0) s_ln[w][kg * 4 + reg] = make_float2(s, q);
    }
    __syncthreads();

    float g[4], be[4];
#pragma unroll
    for (int nt = 0; nt < 4; ++nt) {
        g[nt]  = gamma[w * 64 + nt * 16 + ln15];
        be[nt] = beta[w * 64 + nt * 16 + ln15];
    }
#pragma unroll
    for (int reg = 0; reg < 4; ++reg) {
        int r = kg * 4 + reg;
        float2 p0 = s_ln[0][r], p1 = s_ln[1][r], p2 = s_ln[2][r], p3 = s_ln[3][r];
        float sum = p0.x + p1.x + p2.x + p3.x;
        float sq  = p0.y + p1.y + p2.y + p3.y;
        float mu  = sum * (1.0f / D);
        float var = fmaxf(sq * (1.0f / D) - mu * mu, 0.0f);
        float rstd = rsqrtf(var + 1e-6f);
#pragma unroll
        for (int nt = 0; nt < 4; ++nt) {
            float h = (acc[nt][reg] - mu) * rstd * g[nt] + be[nt];
            H[r][w * 64 + nt * 16 + ln15] = f2bf(h);
        }
    }
    __syncthreads();

    // ---- decoder GEMM: C2[m, e] = sum_d H[m, d] * Wb[e, d], pipelined kt
    f32x4 acc2[4];
#pragma unroll
    for (int et = 0; et < 4; ++et) acc2[et] = (f32x4){0.f, 0.f, 0.f, 0.f};

    short8 afr[8];
#pragma unroll
    for (int kt = 0; kt < 8; ++kt)
        afr[kt] = *(const short8*)&H[ln15][kt * 32 + kg * 8];

    const unsigned short* wbase = Wb + (size_t)(w * 64 + ln15) * D + kg * 8;
    short8 wc0 = *(const short8*)(wbase + 0 * 16 * D);
    short8 wc1 = *(const short8*)(wbase + 1 * 16 * D);
    short8 wc2 = *(const short8*)(wbase + 2 * 16 * D);
    short8 wc3 = *(const short8*)(wbase + 3 * 16 * D);
#pragma unroll
    for (int kt = 0; kt < 8; ++kt) {
        short8 nw0, nw1, nw2, nw3;
        if (kt < 7) {
            const unsigned short* p = wbase + (kt + 1) * 32;
            nw0 = *(const short8*)(p + 0 * 16 * D);
            nw1 = *(const short8*)(p + 1 * 16 * D);
            nw2 = *(const short8*)(p + 2 * 16 * D);
            nw3 = *(const short8*)(p + 3 * 16 * D);
        }
        acc2[0] = __builtin_amdgcn_mfma_f32_16x16x32_bf16(afr[kt], wc0, acc2[0], 0, 0, 0);
        acc2[1] = __builtin_amdgcn_mfma_f32_16x16x32_bf16(afr[kt], wc1, acc2[1], 0, 0, 0);
        acc2[2] = __builtin_amdgcn_mfma_f32_16x16x32_bf16(afr[kt], wc2, acc2[2], 0, 0, 0);
        acc2[3] = __builtin_amdgcn_mfma_f32_16x16x32_bf16(afr[kt], wc3, acc2[3], 0, 0, 0);
        wc0 = nw0; wc1 = nw1; wc2 = nw2; wc3 = nw3;
    }

    // ---- epilogue: relu -> *w_t -> reduce over e -> softplus
    float wt[4];
#pragma unroll
    for (int et = 0; et < 4; ++et) wt[et] = w_t[w * 64 + et * 16 + ln15];
#pragma unroll
    for (int reg = 0; reg < 4; ++reg) {
        float v = 0.f;
#pragma unroll
        for (int et = 0; et < 4; ++et)
            v = fmaf(fmaxf(acc2[et][reg], 0.f), wt[et], v);
#pragma unroll
        for (int m = 1; m < 16; m <<= 1) v += __shfl_xor(v, m);
        if (ln15 == 0) s_dec[w][kg * 4 + reg] = v;
    }
    __syncthreads();
    if (tid < RPB) {
        float tot = s_dec[0][tid] + s_dec[1][tid] + s_dec[2][tid] + s_dec[3][tid] + b_t[0];
        float o = fmaxf(tot, 0.0f) + log1pf(expf(-fabsf(tot)));   // softplus
        out[(size_t)blk * RPB + tid] = o;
    }
}

// ---------------------------------------------------------------------------
extern "C" void kernel_launch(void* const* d_in, const int* in_sizes, int n_in,
                              void* d_out, int out_size, void* d_ws, size_t ws_size,
                              hipStream_t stream) {
    // inputs: 0 event_type(i32) 1 event_time(f32) 2 arrival_times(f32)
    //         3 W_in 4 w_t 5 b_t 6 ln_gamma 7 ln_beta
    const float* t   = (const float*)d_in[1];
    const float* W   = (const float*)d_in[3];
    const float* wt  = (const float*)d_in[4];
    const float* bt  = (const float*)d_in[5];
    const float* gam = (const float*)d_in[6];
    const float* bet = (const float*)d_in[7];
    float* out = (float*)d_out;

    char* ws = (char*)d_ws;
    unsigned short* embT = (unsigned short*)ws;                       // 8 MiB
    unsigned short* Wb   = (unsigned short*)(ws + (size_t)8388608);   // 128 KiB

    embt_kernel<<<dim3(512), dim3(256), 0, stream>>>(t, W, embT, Wb);
    fused_kernel<<<dim3(BATCH * S / RPB), dim3(256), 0, stream>>>(
        t, embT, Wb, gam, bet, wt, bt, out);
}